// Round 4
// baseline (542.945 us; speedup 1.0000x reference)
//
#include <hip/hip_runtime.h>
#include <hip/hip_bf16.h>

// Fused GRU-like cell: 200000 rows, IN=HID=256, fp32 in/out, bf16 MFMA compute.
// Kernel 1 (wconv): convert weights fp32->bf16 into d_ws, fragment-packed per
//                   MFMA B-operand tile; combine biases.
// Kernel 2 (gru):   per-block 64 rows; SIX sequential single-accumulator
//                   matmul passes (z, r, Wh, Uh, G, L) so every pass fits the
//                   128-reg budget of 2 blocks/CU (LDS 64 KB). No spills.

typedef short bf16x8 __attribute__((ext_vector_type(8)));   // 8 bf16 = 4 VGPRs
typedef float f32x4  __attribute__((ext_vector_type(4)));

__device__ __forceinline__ unsigned int rne_bf16(float f) {
  unsigned int u = __builtin_bit_cast(unsigned int, f);
  return (u + 0x7fffu + ((u >> 16) & 1u)) >> 16;
}
__device__ __forceinline__ unsigned int pack2(float a, float b) {
  return rne_bf16(a) | (rne_bf16(b) << 16);
}
__device__ __forceinline__ float bf2f(unsigned short s) {
  unsigned int u = ((unsigned int)s) << 16;
  return __builtin_bit_cast(float, u);
}
__device__ __forceinline__ float sigmoidf_(float v) {
  return 1.f / (1.f + __expf(-v));
}

// ws layout (bf16 shorts), fragment-packed: frag f holds 8 bf16 for lane=f&63
// of tile (nt, kt):  f = (nt*KT + kt)*64 + lane,  n = nt*16+(lane&15),
// k = kt*32+(lane>>4)*8.  Matrix bases (frags): Bz 0, Br 16384, Wh 32768,
// Uh 40960, G 49152, L 57344.  fp32 biases at byte 1048576.
__global__ void wconv_kernel(const float* Wz, const float* Uz, const float* Wr, const float* Ur,
                             const float* Wh, const float* Uh, const float* G, const float* L,
                             const float* bWz, const float* bUz, const float* bWr, const float* bUr,
                             const float* bWh, const float* bUh, const float* bG, const float* bL,
                             const float* bias_h,
                             unsigned short* wb, float* bout) {
  int f = blockIdx.x * blockDim.x + threadIdx.x;   // 65536 fragments
  const float* A; const float* B = nullptr;
  int rel, K;
  if (f < 16384)      { A = Wz; B = Uz; rel = f;         K = 512; }
  else if (f < 32768) { A = Wr; B = Ur; rel = f - 16384; K = 512; }
  else {
    int m = (f - 32768) >> 13; rel = (f - 32768) & 8191; K = 256;
    const float* mats[4] = {Wh, Uh, G, L};
    A = mats[m];
  }
  int lane = rel & 63, tile = rel >> 6;
  int KT = K >> 5;                       // 16 or 8
  int kt = tile & (KT - 1), nt = tile >> (K == 512 ? 4 : 3);
  int n = nt * 16 + (lane & 15);
  int k0 = kt * 32 + (lane >> 4) * 8;
  unsigned short tmp[8];
#pragma unroll
  for (int j = 0; j < 8; ++j) {
    int k = k0 + j;
    float v = (k < 256) ? A[n * 256 + k] : B[n * 256 + (k - 256)];
    tmp[j] = (unsigned short)rne_bf16(v);
  }
  *reinterpret_cast<uint4*>(wb + (size_t)f * 8) = *reinterpret_cast<const uint4*>(tmp);

  if (f < 256) {
    bout[f]        = bWz[f] + bUz[f];
    bout[256 + f]  = bWr[f] + bUr[f];
    bout[512 + f]  = bWh[f] + bUh[f] + bias_h[f];
    bout[768 + f]  = bG[f];
    bout[1024 + f] = bL[f];
  }
}

// Main fused kernel. 512 threads (8 waves). BM=64 rows/block.
// Wave w owns output cols [32w, 32w+32). MFMA 16x16x32 bf16.
// LDS xh[64][512] bf16, XOR-swizzled 16B chunks: chunks 0..31 hold x
// (reused for rh then cand), chunks 32..63 hold h (live to the end).
__global__ __launch_bounds__(512, 4) void gru_kernel(
    const float* __restrict__ x, const float* __restrict__ h,
    const unsigned short* __restrict__ wb,
    const float* __restrict__ bia,
    float* __restrict__ out)
{
  __shared__ unsigned short xh[64 * 512];    // 64 KB total

  const int tid  = threadIdx.x;
  const int lane = tid & 63;
  const int wave = tid >> 6;
  const int q    = lane >> 4;     // quarter-wave id
  const int lr   = lane & 15;
  const long row0 = (long)blockIdx.x * 64;

  // ---------------- Phase 0: stage x,h -> LDS bf16 (swizzled) ----------------
#pragma unroll
  for (int i = 0; i < 4; ++i) {
    int c = tid + i * 512;               // chunk id: 64 rows x 32 chunks
    int r = c >> 5, c8 = c & 31;
    const float4* p = reinterpret_cast<const float4*>(x + (row0 + r) * 256 + c8 * 8);
    float4 v0 = p[0], v1 = p[1];
    uint4 w;
    w.x = pack2(v0.x, v0.y); w.y = pack2(v0.z, v0.w);
    w.z = pack2(v1.x, v1.y); w.w = pack2(v1.z, v1.w);
    reinterpret_cast<uint4*>(xh)[r * 64 + (c8 ^ (r & 7))] = w;
  }
#pragma unroll
  for (int i = 0; i < 4; ++i) {
    int c = tid + i * 512;
    int r = c >> 5, c8 = c & 31;
    const float4* p = reinterpret_cast<const float4*>(h + (row0 + r) * 256 + c8 * 8);
    float4 v0 = p[0], v1 = p[1];
    uint4 w;
    w.x = pack2(v0.x, v0.y); w.y = pack2(v0.z, v0.w);
    w.z = pack2(v1.x, v1.y); w.w = pack2(v1.z, v1.w);
    reinterpret_cast<uint4*>(xh)[r * 64 + ((32 + c8) ^ (r & 7))] = w;
  }
  __syncthreads();

  const unsigned short* Bz = wb;                    // frag-packed bases
  const unsigned short* Br = wb + 131072;
  const unsigned short* Wh = wb + 262144;
  const unsigned short* Uh = wb + 327680;
  const unsigned short* Gw = wb + 393216;
  const unsigned short* Lw = wb + 458752;

  auto ldsA = [&](int mt, int ks) -> bf16x8 {  // A frag from xh (chunk ks*4+q)
    int r = mt * 16 + lr;
    int kc = ks * 4 + q;
    return reinterpret_cast<const bf16x8*>(xh)[r * 64 + (kc ^ (r & 7))];
  };
  auto ldB = [&](const unsigned short* base, int KT, int ct, int ks) -> bf16x8 {
    int nt = wave * 2 + ct;
    return reinterpret_cast<const bf16x8*>(base)[(nt * KT + ks) * 64 + lane];
  };

  const int col0 = wave * 32 + lr;      // ct=0 column

  // ---------------- P1a: z-pass (K=512) -> zpk ----------------
  unsigned int zpk[16];
  {
    f32x4 acc[4][2] = {};
#pragma unroll 2
    for (int ks = 0; ks < 16; ++ks) {
      bf16x8 b0 = ldB(Bz, 16, 0, ks), b1 = ldB(Bz, 16, 1, ks);
#pragma unroll
      for (int mt = 0; mt < 4; ++mt) {
        bf16x8 a = ldsA(mt, ks);
        acc[mt][0] = __builtin_amdgcn_mfma_f32_16x16x32_bf16(a, b0, acc[mt][0], 0, 0, 0);
        acc[mt][1] = __builtin_amdgcn_mfma_f32_16x16x32_bf16(a, b1, acc[mt][1], 0, 0, 0);
      }
    }
#pragma unroll
    for (int mt = 0; mt < 4; ++mt) {
#pragma unroll
      for (int ct = 0; ct < 2; ++ct) {
        int cg = col0 + ct * 16;
        float bzc = bia[cg];
#pragma unroll
        for (int ii = 0; ii < 2; ++ii) {
          float z0 = sigmoidf_(acc[mt][ct][2 * ii]     + bzc);
          float z1 = sigmoidf_(acc[mt][ct][2 * ii + 1] + bzc);
          zpk[(mt * 2 + ct) * 2 + ii] = pack2(z0, z1);
        }
      }
    }
  }

  // ---------------- P1b: r-pass (K=512) -> rhpk = bf16(r*h) ----------------
  unsigned int rhpk[16];
  {
    f32x4 acc[4][2] = {};
#pragma unroll 2
    for (int ks = 0; ks < 16; ++ks) {
      bf16x8 b0 = ldB(Br, 16, 0, ks), b1 = ldB(Br, 16, 1, ks);
#pragma unroll
      for (int mt = 0; mt < 4; ++mt) {
        bf16x8 a = ldsA(mt, ks);
        acc[mt][0] = __builtin_amdgcn_mfma_f32_16x16x32_bf16(a, b0, acc[mt][0], 0, 0, 0);
        acc[mt][1] = __builtin_amdgcn_mfma_f32_16x16x32_bf16(a, b1, acc[mt][1], 0, 0, 0);
      }
    }
#pragma unroll
    for (int mt = 0; mt < 4; ++mt) {
#pragma unroll
      for (int ct = 0; ct < 2; ++ct) {
        int cg = col0 + ct * 16;
        float brc = bia[256 + cg];
        int hc = 32 + (cg >> 3);
#pragma unroll
        for (int ii = 0; ii < 2; ++ii) {
          int rl0 = mt * 16 + q * 4 + 2 * ii;
          float r0 = sigmoidf_(acc[mt][ct][2 * ii]     + brc);
          float r1 = sigmoidf_(acc[mt][ct][2 * ii + 1] + brc);
          float h0 = bf2f(xh[rl0 * 512       + (hc ^ (rl0 & 7))       * 8 + (cg & 7)]);
          float h1 = bf2f(xh[(rl0 + 1) * 512 + (hc ^ ((rl0 + 1) & 7)) * 8 + (cg & 7)]);
          rhpk[(mt * 2 + ct) * 2 + ii] = pack2(r0 * h0, r1 * h1);
        }
      }
    }
  }

  // ---------------- P2: ac = x @ Wh^T (K=256, x region) ----------------
  f32x4 ac[4][2] = {};
#pragma unroll 2
  for (int ks = 0; ks < 8; ++ks) {
    bf16x8 b0 = ldB(Wh, 8, 0, ks), b1 = ldB(Wh, 8, 1, ks);
#pragma unroll
    for (int mt = 0; mt < 4; ++mt) {
      bf16x8 a = ldsA(mt, ks);
      ac[mt][0] = __builtin_amdgcn_mfma_f32_16x16x32_bf16(a, b0, ac[mt][0], 0, 0, 0);
      ac[mt][1] = __builtin_amdgcn_mfma_f32_16x16x32_bf16(a, b1, ac[mt][1], 0, 0, 0);
    }
  }
  __syncthreads();   // all waves done reading x

  // write rh (bf16 bits straight from rhpk) into the x region
#pragma unroll
  for (int mt = 0; mt < 4; ++mt) {
#pragma unroll
    for (int ct = 0; ct < 2; ++ct) {
      int cg = col0 + ct * 16;
#pragma unroll
      for (int ii = 0; ii < 2; ++ii) {
        unsigned int v = rhpk[(mt * 2 + ct) * 2 + ii];
        int rl0 = mt * 16 + q * 4 + 2 * ii;
        xh[rl0 * 512       + (((cg >> 3) ^ (rl0 & 7))       * 8) + (cg & 7)] = (unsigned short)(v & 0xffffu);
        xh[(rl0 + 1) * 512 + (((cg >> 3) ^ ((rl0 + 1) & 7)) * 8) + (cg & 7)] = (unsigned short)(v >> 16);
      }
    }
  }
  __syncthreads();

  // ---------------- P3: ac += rh @ Uh^T (K=256) ----------------
#pragma unroll 2
  for (int ks = 0; ks < 8; ++ks) {
    bf16x8 b0 = ldB(Uh, 8, 0, ks), b1 = ldB(Uh, 8, 1, ks);
#pragma unroll
    for (int mt = 0; mt < 4; ++mt) {
      bf16x8 a = ldsA(mt, ks);
      ac[mt][0] = __builtin_amdgcn_mfma_f32_16x16x32_bf16(a, b0, ac[mt][0], 0, 0, 0);
      ac[mt][1] = __builtin_amdgcn_mfma_f32_16x16x32_bf16(a, b1, ac[mt][1], 0, 0, 0);
    }
  }
  __syncthreads();   // all reads of rh done before overwrite

  // cand = ac + bias -> bf16 into same region
#pragma unroll
  for (int mt = 0; mt < 4; ++mt) {
#pragma unroll
    for (int ct = 0; ct < 2; ++ct) {
      int cg = col0 + ct * 16;
      float bcc = bia[512 + cg];
#pragma unroll
      for (int i = 0; i < 4; ++i) {
        int rl = mt * 16 + q * 4 + i;
        float cd = ac[mt][ct][i] + bcc;
        xh[rl * 512 + (((cg >> 3) ^ (rl & 7)) * 8) + (cg & 7)] = (unsigned short)rne_bf16(cd);
      }
    }
  }
  __syncthreads();

  // ---------------- P4: gate pass (K=256) -> gv (f32, reuse acc) ----------------
  f32x4 gv[4][2];
  {
    f32x4 acc[4][2] = {};
#pragma unroll 2
    for (int ks = 0; ks < 8; ++ks) {
      bf16x8 b0 = ldB(Gw, 8, 0, ks), b1 = ldB(Gw, 8, 1, ks);
#pragma unroll
      for (int mt = 0; mt < 4; ++mt) {
        bf16x8 a = ldsA(mt, ks);
        acc[mt][0] = __builtin_amdgcn_mfma_f32_16x16x32_bf16(a, b0, acc[mt][0], 0, 0, 0);
        acc[mt][1] = __builtin_amdgcn_mfma_f32_16x16x32_bf16(a, b1, acc[mt][1], 0, 0, 0);
      }
    }
#pragma unroll
    for (int mt = 0; mt < 4; ++mt) {
#pragma unroll
      for (int ct = 0; ct < 2; ++ct) {
        float bgc = bia[768 + col0 + ct * 16];
#pragma unroll
        for (int i = 0; i < 4; ++i)
          gv[mt][ct][i] = sigmoidf_(acc[mt][ct][i] + bgc);
      }
    }
  }

  // ---------------- P5: linear pass (K=256) + epilogue ----------------
  {
    f32x4 acc[4][2] = {};
#pragma unroll 2
    for (int ks = 0; ks < 8; ++ks) {
      bf16x8 b0 = ldB(Lw, 8, 0, ks), b1 = ldB(Lw, 8, 1, ks);
#pragma unroll
      for (int mt = 0; mt < 4; ++mt) {
        bf16x8 a = ldsA(mt, ks);
        acc[mt][0] = __builtin_amdgcn_mfma_f32_16x16x32_bf16(a, b0, acc[mt][0], 0, 0, 0);
        acc[mt][1] = __builtin_amdgcn_mfma_f32_16x16x32_bf16(a, b1, acc[mt][1], 0, 0, 0);
      }
    }
#pragma unroll
    for (int mt = 0; mt < 4; ++mt) {
#pragma unroll
      for (int ct = 0; ct < 2; ++ct) {
        int cg = col0 + ct * 16;
        float blc = bia[1024 + cg];
        int hc = 32 + (cg >> 3);
#pragma unroll
        for (int ii = 0; ii < 2; ++ii) {
          unsigned int zp = zpk[(mt * 2 + ct) * 2 + ii];
#pragma unroll
          for (int j = 0; j < 2; ++j) {
            int i = 2 * ii + j;
            int rl = mt * 16 + q * 4 + i;
            float lv = acc[mt][ct][i] + blc;
            float cand = lv * gv[mt][ct][i];
            float zv = bf2f((unsigned short)(j == 0 ? (zp & 0xffffu) : (zp >> 16)));
            float hval = bf2f(xh[rl * 512 + (hc ^ (rl & 7)) * 8 + (cg & 7)]);
            out[(row0 + rl) * 256 + cg] = zv * cand + (1.f - zv) * hval;
          }
        }
      }
    }
  }
}

extern "C" void kernel_launch(void* const* d_in, const int* in_sizes, int n_in,
                              void* d_out, int out_size, void* d_ws, size_t ws_size,
                              hipStream_t stream) {
  const float* x   = (const float*)d_in[0];
  const float* h   = (const float*)d_in[1];
  const float* Wz  = (const float*)d_in[2];  const float* bWz = (const float*)d_in[3];
  const float* Uz  = (const float*)d_in[4];  const float* bUz = (const float*)d_in[5];
  const float* Wr  = (const float*)d_in[6];  const float* bWr = (const float*)d_in[7];
  const float* Ur  = (const float*)d_in[8];  const float* bUr = (const float*)d_in[9];
  const float* Wh  = (const float*)d_in[10]; const float* bWh = (const float*)d_in[11];
  const float* Uh  = (const float*)d_in[12]; const float* bUh = (const float*)d_in[13];
  const float* G   = (const float*)d_in[14]; const float* bG  = (const float*)d_in[15];
  const float* L   = (const float*)d_in[16]; const float* bL  = (const float*)d_in[17];
  const float* bh  = (const float*)d_in[18];

  unsigned short* wb = (unsigned short*)d_ws;
  float* bia = (float*)((char*)d_ws + 1048576);

  wconv_kernel<<<256, 256, 0, stream>>>(Wz, Uz, Wr, Ur, Wh, Uh, G, L,
                                        bWz, bUz, bWr, bUr, bWh, bUh, bG, bL, bh,
                                        wb, bia);

  int rows = in_sizes[0] / 256;        // 200000
  int grid = rows / 64;                // 3125 (exact)
  gru_kernel<<<grid, 512, 0, stream>>>(x, h, wb, bia, (float*)d_out);
}

// Round 5
// 487.189 us; speedup vs baseline: 1.1144x; 1.1144x over previous
//
#include <hip/hip_runtime.h>
#include <hip/hip_bf16.h>

// Fused GRU-like cell: 200000 rows, IN=HID=256, fp32 in/out, bf16 MFMA compute.
// Kernel 1 (wconv): fp32->bf16 weights, fragment-packed; combined biases.
//   Matrices: Bz=[Wz|Uz] (K=512), Br=[Wr|Ur] (K=512), Bh=[Wh|Uh] (K=512),
//             G (K=256), L (K=256).
// Kernel 2 (gru): per-block 64 rows, 3 matmul passes:
//   P1  : z,r   = sig([x|h]·Bz^T), sig([x|h]·Br^T)      (merged, K=512)
//   P23 : cand  = [x|r.h]·Bh^T                           (K=512, rh in dead h-region)
//   P45 : gate,lin = cand·G^T, cand·L^T                  (merged, K=256, cand in dead x-region)
//   h pointwise values come from GLOBAL fp32 (L2-hot) - no scalar LDS reads.

typedef short bf16x8 __attribute__((ext_vector_type(8)));   // 8 bf16 = 4 VGPRs
typedef float f32x4  __attribute__((ext_vector_type(4)));

__device__ __forceinline__ unsigned int rne_bf16(float f) {
  unsigned int u = __builtin_bit_cast(unsigned int, f);
  return (u + 0x7fffu + ((u >> 16) & 1u)) >> 16;
}
__device__ __forceinline__ unsigned int pack2(float a, float b) {
  return rne_bf16(a) | (rne_bf16(b) << 16);
}
__device__ __forceinline__ float bf2f(unsigned short s) {
  unsigned int u = ((unsigned int)s) << 16;
  return __builtin_bit_cast(float, u);
}
__device__ __forceinline__ float sigmoidf_(float v) {
  return 1.f / (1.f + __expf(-v));
}

// Fragment packing: frag f holds 8 bf16 for lane=f&63 of tile (nt,kt):
// f = base + (nt*KT + kt)*64 + lane, n = nt*16+(lane&15), k = kt*32+(lane>>4)*8.
// Frag bases: Bz 0, Br 16384, Bh 32768, G 49152, L 57344. Biases @ byte 1048576.
__global__ void wconv_kernel(const float* Wz, const float* Uz, const float* Wr, const float* Ur,
                             const float* Wh, const float* Uh, const float* G, const float* L,
                             const float* bWz, const float* bUz, const float* bWr, const float* bUr,
                             const float* bWh, const float* bUh, const float* bG, const float* bL,
                             const float* bias_h,
                             unsigned short* wb, float* bout) {
  int f = blockIdx.x * blockDim.x + threadIdx.x;   // 65536 fragments
  const float* A; const float* B = nullptr;
  int rel; bool k512;
  if (f < 16384)      { A = Wz; B = Uz; rel = f;         k512 = true;  }
  else if (f < 32768) { A = Wr; B = Ur; rel = f - 16384; k512 = true;  }
  else if (f < 49152) { A = Wh; B = Uh; rel = f - 32768; k512 = true;  }
  else if (f < 57344) { A = G;          rel = f - 49152; k512 = false; }
  else                { A = L;          rel = f - 57344; k512 = false; }
  int lane = rel & 63, tile = rel >> 6;
  int kt = k512 ? (tile & 15) : (tile & 7);
  int nt = k512 ? (tile >> 4) : (tile >> 3);
  int n = nt * 16 + (lane & 15);
  int k0 = kt * 32 + (lane >> 4) * 8;
  unsigned short tmp[8];
#pragma unroll
  for (int j = 0; j < 8; ++j) {
    int k = k0 + j;
    float v = (k < 256) ? A[n * 256 + k] : B[n * 256 + (k - 256)];
    tmp[j] = (unsigned short)rne_bf16(v);
  }
  *reinterpret_cast<uint4*>(wb + (size_t)f * 8) = *reinterpret_cast<const uint4*>(tmp);

  if (f < 256) {
    bout[f]        = bWz[f] + bUz[f];
    bout[256 + f]  = bWr[f] + bUr[f];
    bout[512 + f]  = bWh[f] + bUh[f] + bias_h[f];
    bout[768 + f]  = bG[f];
    bout[1024 + f] = bL[f];
  }
}

// Main fused kernel. 512 threads (8 waves). BM=64 rows/block.
// Wave w owns output cols [32w, 32w+32). MFMA 16x16x32 bf16.
// LDS xh[64][512] bf16, XOR-swizzled 16B chunks: chunks 0..31 = x (later cand),
// chunks 32..63 = h (later r.h).
__global__ __launch_bounds__(512, 4) void gru_kernel(
    const float* __restrict__ x, const float* __restrict__ h,
    const unsigned short* __restrict__ wb,
    const float* __restrict__ bia,
    float* __restrict__ out)
{
  __shared__ unsigned short xh[64 * 512];    // 64 KB

  const int tid  = threadIdx.x;
  const int lane = tid & 63;
  const int wave = tid >> 6;
  const int q    = lane >> 4;     // quarter-wave id
  const int lr   = lane & 15;
  const long row0 = (long)blockIdx.x * 64;

  // ---------------- P0: stage x,h -> LDS bf16 (swizzled) ----------------
#pragma unroll
  for (int i = 0; i < 4; ++i) {
    int c = tid + i * 512;               // 64 rows x 32 chunks
    int r = c >> 5, c8 = c & 31;
    const float4* p = reinterpret_cast<const float4*>(x + (row0 + r) * 256 + c8 * 8);
    float4 v0 = p[0], v1 = p[1];
    uint4 w;
    w.x = pack2(v0.x, v0.y); w.y = pack2(v0.z, v0.w);
    w.z = pack2(v1.x, v1.y); w.w = pack2(v1.z, v1.w);
    reinterpret_cast<uint4*>(xh)[r * 64 + (c8 ^ (r & 7))] = w;
  }
#pragma unroll
  for (int i = 0; i < 4; ++i) {
    int c = tid + i * 512;
    int r = c >> 5, c8 = c & 31;
    const float4* p = reinterpret_cast<const float4*>(h + (row0 + r) * 256 + c8 * 8);
    float4 v0 = p[0], v1 = p[1];
    uint4 w;
    w.x = pack2(v0.x, v0.y); w.y = pack2(v0.z, v0.w);
    w.z = pack2(v1.x, v1.y); w.w = pack2(v1.z, v1.w);
    reinterpret_cast<uint4*>(xh)[r * 64 + ((32 + c8) ^ (r & 7))] = w;
  }
  __syncthreads();

  const unsigned short* Bz = wb;                    // frag-packed bases (shorts)
  const unsigned short* Br = wb + 131072;
  const unsigned short* Bh = wb + 262144;
  const unsigned short* Gw = wb + 393216;
  const unsigned short* Lw = wb + 458752;

  auto ldsA = [&](int mt, int ks) -> bf16x8 {  // A frag, chunk ks*4+q
    int r = mt * 16 + lr;
    int kc = ks * 4 + q;
    return reinterpret_cast<const bf16x8*>(xh)[r * 64 + (kc ^ (r & 7))];
  };
  auto ldB = [&](const unsigned short* base, int KT, int ct, int ks) -> bf16x8 {
    int nt = wave * 2 + ct;
    return reinterpret_cast<const bf16x8*>(base)[(nt * KT + ks) * 64 + lane];
  };

  const int col0 = wave * 32 + lr;      // ct=0 column

  // ---------------- P1: merged z + r (K=512) ----------------
  unsigned int zpk[16], rhpk[16];
  {
    f32x4 az[4][2] = {}; f32x4 ar[4][2] = {};
    bf16x8 bz0 = ldB(Bz, 16, 0, 0), bz1 = ldB(Bz, 16, 1, 0);
    bf16x8 br0 = ldB(Br, 16, 0, 0), br1 = ldB(Br, 16, 1, 0);
#pragma unroll
    for (int ks = 0; ks < 16; ++ks) {
      bf16x8 nz0, nz1, nr0, nr1;
      if (ks < 15) {
        nz0 = ldB(Bz, 16, 0, ks + 1); nz1 = ldB(Bz, 16, 1, ks + 1);
        nr0 = ldB(Br, 16, 0, ks + 1); nr1 = ldB(Br, 16, 1, ks + 1);
      }
#pragma unroll
      for (int mt = 0; mt < 4; ++mt) {
        bf16x8 a = ldsA(mt, ks);
        az[mt][0] = __builtin_amdgcn_mfma_f32_16x16x32_bf16(a, bz0, az[mt][0], 0, 0, 0);
        az[mt][1] = __builtin_amdgcn_mfma_f32_16x16x32_bf16(a, bz1, az[mt][1], 0, 0, 0);
        ar[mt][0] = __builtin_amdgcn_mfma_f32_16x16x32_bf16(a, br0, ar[mt][0], 0, 0, 0);
        ar[mt][1] = __builtin_amdgcn_mfma_f32_16x16x32_bf16(a, br1, ar[mt][1], 0, 0, 0);
      }
      bz0 = nz0; bz1 = nz1; br0 = nr0; br1 = nr1;
    }
    // z -> zpk (bf16 pair); r*h (h from GLOBAL fp32) -> rhpk
#pragma unroll
    for (int mt = 0; mt < 4; ++mt) {
#pragma unroll
      for (int ct = 0; ct < 2; ++ct) {
        int cg = col0 + ct * 16;
        float bzc = bia[cg];
        float brc = bia[256 + cg];
#pragma unroll
        for (int ii = 0; ii < 2; ++ii) {
          int rl0 = mt * 16 + q * 4 + 2 * ii;
          float z0 = sigmoidf_(az[mt][ct][2 * ii]     + bzc);
          float z1 = sigmoidf_(az[mt][ct][2 * ii + 1] + bzc);
          zpk[(mt * 2 + ct) * 2 + ii] = pack2(z0, z1);
          float r0 = sigmoidf_(ar[mt][ct][2 * ii]     + brc);
          float r1 = sigmoidf_(ar[mt][ct][2 * ii + 1] + brc);
          float h0 = h[(row0 + rl0) * 256 + cg];
          float h1 = h[(row0 + rl0 + 1) * 256 + cg];
          rhpk[(mt * 2 + ct) * 2 + ii] = pack2(r0 * h0, r1 * h1);
        }
      }
    }
  }
  __syncthreads();   // all waves done reading h-region (P1 A-frags)

  // write r.h into the dead h-region (chunks 32..63)
#pragma unroll
  for (int mt = 0; mt < 4; ++mt) {
#pragma unroll
    for (int ct = 0; ct < 2; ++ct) {
      int cg = col0 + ct * 16;
      int hc = 32 + (cg >> 3);
#pragma unroll
      for (int ii = 0; ii < 2; ++ii) {
        unsigned int v = rhpk[(mt * 2 + ct) * 2 + ii];
        int rl0 = mt * 16 + q * 4 + 2 * ii;
        xh[rl0 * 512       + (hc ^ (rl0 & 7))       * 8 + (cg & 7)] = (unsigned short)(v & 0xffffu);
        xh[(rl0 + 1) * 512 + (hc ^ ((rl0 + 1) & 7)) * 8 + (cg & 7)] = (unsigned short)(v >> 16);
      }
    }
  }
  __syncthreads();

  // ---------------- P23: cand = [x|r.h] @ Bh^T (K=512) ----------------
  {
    f32x4 ac[4][2] = {};
    bf16x8 b0 = ldB(Bh, 16, 0, 0), b1 = ldB(Bh, 16, 1, 0);
#pragma unroll
    for (int ks = 0; ks < 16; ++ks) {
      bf16x8 n0, n1;
      if (ks < 15) { n0 = ldB(Bh, 16, 0, ks + 1); n1 = ldB(Bh, 16, 1, ks + 1); }
#pragma unroll
      for (int mt = 0; mt < 4; ++mt) {
        bf16x8 a = ldsA(mt, ks);
        ac[mt][0] = __builtin_amdgcn_mfma_f32_16x16x32_bf16(a, b0, ac[mt][0], 0, 0, 0);
        ac[mt][1] = __builtin_amdgcn_mfma_f32_16x16x32_bf16(a, b1, ac[mt][1], 0, 0, 0);
      }
      b0 = n0; b1 = n1;
    }
    __syncthreads();   // all waves done reading x-region (P23 A-frags)
    // cand -> bf16 into the dead x-region (chunks 0..31)
#pragma unroll
    for (int mt = 0; mt < 4; ++mt) {
#pragma unroll
      for (int ct = 0; ct < 2; ++ct) {
        int cg = col0 + ct * 16;
        float bcc = bia[512 + cg];
#pragma unroll
        for (int i = 0; i < 4; ++i) {
          int rl = mt * 16 + q * 4 + i;
          float cd = ac[mt][ct][i] + bcc;
          xh[rl * 512 + (((cg >> 3) ^ (rl & 7)) * 8) + (cg & 7)] = (unsigned short)rne_bf16(cd);
        }
      }
    }
  }
  __syncthreads();

  // ---------------- P45: merged gate + linear (K=256, cand region) ----------------
  {
    f32x4 ag[4][2] = {}; f32x4 al[4][2] = {};
#pragma unroll 2
    for (int ks = 0; ks < 8; ++ks) {
      bf16x8 bg0 = ldB(Gw, 8, 0, ks), bg1 = ldB(Gw, 8, 1, ks);
      bf16x8 bl0 = ldB(Lw, 8, 0, ks), bl1 = ldB(Lw, 8, 1, ks);
#pragma unroll
      for (int mt = 0; mt < 4; ++mt) {
        bf16x8 a = ldsA(mt, ks);
        ag[mt][0] = __builtin_amdgcn_mfma_f32_16x16x32_bf16(a, bg0, ag[mt][0], 0, 0, 0);
        ag[mt][1] = __builtin_amdgcn_mfma_f32_16x16x32_bf16(a, bg1, ag[mt][1], 0, 0, 0);
        al[mt][0] = __builtin_amdgcn_mfma_f32_16x16x32_bf16(a, bl0, al[mt][0], 0, 0, 0);
        al[mt][1] = __builtin_amdgcn_mfma_f32_16x16x32_bf16(a, bl1, al[mt][1], 0, 0, 0);
      }
    }

    // ---------------- epilogue: out = z*(lin*gate) + (1-z)*h ----------------
#pragma unroll
    for (int mt = 0; mt < 4; ++mt) {
#pragma unroll
      for (int ct = 0; ct < 2; ++ct) {
        int cg = col0 + ct * 16;
        float bgc = bia[768 + cg];
        float blc = bia[1024 + cg];
#pragma unroll
        for (int ii = 0; ii < 2; ++ii) {
          unsigned int zp = zpk[(mt * 2 + ct) * 2 + ii];
#pragma unroll
          for (int j = 0; j < 2; ++j) {
            int i = 2 * ii + j;
            int rl = mt * 16 + q * 4 + i;
            float gv = sigmoidf_(ag[mt][ct][i] + bgc);
            float lv = al[mt][ct][i] + blc;
            float cand = lv * gv;
            float zv = bf2f((unsigned short)(j == 0 ? (zp & 0xffffu) : (zp >> 16)));
            float hval = h[(row0 + rl) * 256 + cg];
            out[(row0 + rl) * 256 + cg] = zv * cand + (1.f - zv) * hval;
          }
        }
      }
    }
  }
}

extern "C" void kernel_launch(void* const* d_in, const int* in_sizes, int n_in,
                              void* d_out, int out_size, void* d_ws, size_t ws_size,
                              hipStream_t stream) {
  const float* x   = (const float*)d_in[0];
  const float* h   = (const float*)d_in[1];
  const float* Wz  = (const float*)d_in[2];  const float* bWz = (const float*)d_in[3];
  const float* Uz  = (const float*)d_in[4];  const float* bUz = (const float*)d_in[5];
  const float* Wr  = (const float*)d_in[6];  const float* bWr = (const float*)d_in[7];
  const float* Ur  = (const float*)d_in[8];  const float* bUr = (const float*)d_in[9];
  const float* Wh  = (const float*)d_in[10]; const float* bWh = (const float*)d_in[11];
  const float* Uh  = (const float*)d_in[12]; const float* bUh = (const float*)d_in[13];
  const float* G   = (const float*)d_in[14]; const float* bG  = (const float*)d_in[15];
  const float* L   = (const float*)d_in[16]; const float* bL  = (const float*)d_in[17];
  const float* bh  = (const float*)d_in[18];

  unsigned short* wb = (unsigned short*)d_ws;
  float* bia = (float*)((char*)d_ws + 1048576);

  wconv_kernel<<<256, 256, 0, stream>>>(Wz, Uz, Wr, Ur, Wh, Uh, G, L,
                                        bWz, bUz, bWr, bUr, bWh, bUh, bG, bL, bh,
                                        wb, bia);

  int rows = in_sizes[0] / 256;        // 200000
  int grid = rows / 64;                // 3125 (exact)
  gru_kernel<<<grid, 512, 0, stream>>>(x, h, wb, bia, (float*)d_out);
}